// Round 3
// baseline (305.305 us; speedup 1.0000x reference)
//
#include <hip/hip_runtime.h>

// SharedAdditiveKAN: y = spline(x) @ mix^T + bias
// x: [65536, 512] fp32; bases/slopes: [512, 16] fp32; mix: [512, 512] fp32; bias: [512] fp32
// y: [65536, 512] fp32.
//
// R3: split into (1) streaming spline pass (fp32 x -> bf16 spline in ws) and
// (2) canonical 128x128x64 bf16 MFMA GEMM at 4 blocks/CU. R2's fused kernel
// was latency-bound (HBM 27%, Mfma 14%, VALU 20%): s_tab(35K)+sB(32K) forced
// 2 blocks/CU and 2 full-drain barriers per kt couldn't be hidden.
// Fallback to the fused kernel if ws is too small for the 64 MB intermediate.

#define DIMK 512
#define DIMN 512

typedef unsigned short u16;
typedef unsigned int u32;
typedef __attribute__((ext_vector_type(8))) __bf16 bf16x8;
typedef __attribute__((ext_vector_type(4))) float f32x4;

__device__ __forceinline__ u32 bf16rne(float f) {
    u32 u = __float_as_uint(f);
    return (u + 0x7fffu + ((u >> 16) & 1u)) >> 16;  // round-to-nearest-even
}

// ---- prep: mix fp32 -> bf16 bits ----
__global__ void prep_kernel(const float* __restrict__ mix,
                            u16* __restrict__ mixb) {
    int t = blockIdx.x * 256 + threadIdx.x;             // 65536 threads
    float4 v = reinterpret_cast<const float4*>(mix)[t];
    ushort4 o;
    o.x = (u16)bf16rne(v.x);
    o.y = (u16)bf16rne(v.y);
    o.z = (u16)bf16rne(v.z);
    o.w = (u16)bf16rne(v.w);
    reinterpret_cast<ushort4*>(mixb)[t] = o;
}

// ---- pass 1: spline, pure streaming. 1024 blocks x 256 thr, 32 f4/thread ----
__global__ __launch_bounds__(256) void spline_kernel(
    const float* __restrict__ x, const float* __restrict__ bases,
    const float* __restrict__ slopes, u16* __restrict__ spl) {
    // (base,slope) bf16-pair table, stride 17 words/dim to spread banks
    __shared__ u32 s_tab[DIMK * 17];  // 34.8 KB -> 4 blocks/CU

    const int tid = threadIdx.x;
#pragma unroll
    for (int k = 0; k < 32; k++) {
        int i = tid + k * 256;  // 0..8191 over [D=512][G=16]
        s_tab[(i >> 4) * 17 + (i & 15)] = bf16rne(bases[i]) | (bf16rne(slopes[i]) << 16);
    }
    __syncthreads();

    size_t base = (size_t)blockIdx.x * 8192;  // float4 index
#pragma unroll 2
    for (int it = 0; it < 32; it++) {
        size_t f4 = base + it * 256 + tid;
        float4 v = reinterpret_cast<const float4*>(x)[f4];
        int d0 = ((int)(f4 & 127)) * 4;  // dim of v.x (row = 512 fp32 = 128 f4)
        float xs[4] = {v.x, v.y, v.z, v.w};
        u32 h[4];
#pragma unroll
        for (int j = 0; j < 4; j++) {
            // EXACT reference index math (fp32): x_norm=clip((x+1)*0.5,0,0.999999);
            // t=x_norm*16; idx=trunc(t). (*0.5, *16 exact -> idx matches numpy.)
            float xn = fminf(fmaxf((xs[j] + 1.0f) * 0.5f, 0.0f), 0.999999f);
            float tt = xn * 16.0f;
            int idx = (int)tt;
            u32 p = s_tab[(d0 + j) * 17 + idx];
            float b = __uint_as_float(p << 16);
            float s = __uint_as_float(p & 0xffff0000u);
            h[j] = bf16rne(fmaf(s, tt - (float)idx, b));
        }
        ushort4 o;
        o.x = (u16)h[0]; o.y = (u16)h[1]; o.z = (u16)h[2]; o.w = (u16)h[3];
        reinterpret_cast<ushort4*>(spl)[f4] = o;
    }
}

// ---- pass 2: y = spl(bf16) @ mixb^T + bias. BM=BN=128, BK=64, 256 thr ----
// LDS 32 KB -> 4+ blocks/CU; 4 waves (2m x 2n), wave tile 64x64, acc 64/lane.
// XOR swizzle: row r (128 B = 8 chunks of 16 B), chunk c stored at c^(r&7).
// glds width=16 writes base+lane*16 => global source chunk = (lane&7)^(r&7).
// Frag b128 reads: 16 rows x chunk ((ks<<2)|quad)^(r&7) -> 2-way banks (free).
__global__ __launch_bounds__(256, 4) void gemm_kernel(
    const u16* __restrict__ spl, const u16* __restrict__ mixb,
    const float* __restrict__ bias, float* __restrict__ y) {
    __shared__ __align__(16) u16 sA[128 * 64];  // 16 KB
    __shared__ __align__(16) u16 sB[128 * 64];  // 16 KB

    const int tid = threadIdx.x;
    const int lane = tid & 63;
    const int wid = tid >> 6;   // 0..3
    const int quad = lane >> 4;
    const int l15 = lane & 15;
    const int wave_m = wid >> 1;
    const int wave_n = wid & 1;
    const int m0 = blockIdx.x * 128;  // grid (512, 4): n-pass-major dispatch
    const int n0 = blockIdx.y * 128;  //  -> A LLC-hot on passes 1-3, B L2-hot

    f32x4 acc[4][4];
#pragma unroll
    for (int i = 0; i < 4; i++)
#pragma unroll
        for (int j = 0; j < 4; j++) acc[i][j] = (f32x4){0.f, 0.f, 0.f, 0.f};

    // glds source lane mapping (shared by A and B tiles)
    const int grow = (lane >> 3);        // row within 8-row group
    const int gcg = (lane & 7);          // local chunk = lane&7

    for (int kt = 0; kt < 8; ++kt) {
        const int k0 = kt * 64;
#pragma unroll
        for (int i = 0; i < 4; i++) {
            int g = wid * 4 + i;  // 0..15: 8-row group
            int row = g * 8 + grow;
            int cg = gcg ^ (row & 7);  // global chunk so LDS lands swizzled
            const u16* srcA = spl + (size_t)(m0 + row) * DIMK + k0 + cg * 8;
            const u16* srcB = mixb + (size_t)(n0 + row) * DIMK + k0 + cg * 8;
            __builtin_amdgcn_global_load_lds(
                (const __attribute__((address_space(1))) void*)srcA,
                (__attribute__((address_space(3))) void*)((char*)sA + g * 1024),
                16, 0, 0);
            __builtin_amdgcn_global_load_lds(
                (const __attribute__((address_space(1))) void*)srcB,
                (__attribute__((address_space(3))) void*)((char*)sB + g * 1024),
                16, 0, 0);
        }
        __syncthreads();

#pragma unroll
        for (int ks = 0; ks < 2; ks++) {
            bf16x8 af[4], bf[4];
#pragma unroll
            for (int fm = 0; fm < 4; fm++) {
                int row = wave_m * 64 + fm * 16 + l15;
                int c = ((ks << 2) | quad) ^ (row & 7);
                af[fm] = *reinterpret_cast<const bf16x8*>(&sA[row * 64 + c * 8]);
            }
#pragma unroll
            for (int fn = 0; fn < 4; fn++) {
                int row = wave_n * 64 + fn * 16 + l15;
                int c = ((ks << 2) | quad) ^ (row & 7);
                bf[fn] = *reinterpret_cast<const bf16x8*>(&sB[row * 64 + c * 8]);
            }
#pragma unroll
            for (int fn = 0; fn < 4; fn++)
#pragma unroll
                for (int fm = 0; fm < 4; fm++)
                    acc[fm][fn] = __builtin_amdgcn_mfma_f32_16x16x32_bf16(
                        af[fm], bf[fn], acc[fm][fn], 0, 0, 0);
        }
        __syncthreads();
    }

    // epilogue: C/D layout col=lane&15, row=quad*4+j
#pragma unroll
    for (int fn = 0; fn < 4; fn++) {
        int o = n0 + wave_n * 64 + fn * 16 + l15;
        float bv = bias[o];
#pragma unroll
        for (int fm = 0; fm < 4; fm++) {
            int r0 = m0 + wave_m * 64 + fm * 16 + quad * 4;
            float* yp = y + (size_t)r0 * DIMN + o;
#pragma unroll
            for (int j = 0; j < 4; j++)
                yp[(size_t)j * DIMN] = acc[fm][fn][j] + bv;
        }
    }
}

// ==================== fallback: R2 fused kernel ====================
__global__ __launch_bounds__(512, 2) void kan_kernel(
    const float* __restrict__ x, const float* __restrict__ bases,
    const float* __restrict__ slopes, const u16* __restrict__ mixb,
    const float* __restrict__ bias, float* __restrict__ y) {
    __shared__ u32 s_tab[DIMK * 17];
    __shared__ __align__(16) u16 sA[128 * 32];
    __shared__ __align__(16) u16 sB[512 * 32];

    const int tid = threadIdx.x;
    const int lane = tid & 63;
    const int wid = tid >> 6;
    const int quad = lane >> 4;
    const int l15 = lane & 15;
    const int wave_m = wid >> 2;
    const int wave_n = wid & 3;
    const int m0 = blockIdx.x * 128;

#pragma unroll
    for (int k = 0; k < 16; k++) {
        int i = tid + k * 512;
        s_tab[(i >> 4) * 17 + (i & 15)] = bf16rne(bases[i]) | (bf16rne(slopes[i]) << 16);
    }

    const int ar = tid >> 2;
    const int akg = tid & 3;
    const int awchunk = (ar << 2) | (akg ^ ((ar >> 1) & 3));
    const float4* xrow =
        reinterpret_cast<const float4*>(x + (size_t)(m0 + ar) * DIMK) + akg * 2;

    f32x4 acc[4][8];
#pragma unroll
    for (int i = 0; i < 4; i++)
#pragma unroll
        for (int j = 0; j < 8; j++) acc[i][j] = (f32x4){0.f, 0.f, 0.f, 0.f};

    float4 xa = xrow[0];
    float4 xb = xrow[1];
    __syncthreads();

    for (int kt = 0; kt < 16; ++kt) {
        float xs[8] = {xa.x, xa.y, xa.z, xa.w, xb.x, xb.y, xb.z, xb.w};
        const int dbase = kt * 32 + akg * 8;
        u32 h[8];
#pragma unroll
        for (int j = 0; j < 8; j++) {
            float xn = fminf(fmaxf((xs[j] + 1.0f) * 0.5f, 0.0f), 0.999999f);
            float tt = xn * 16.0f;
            int idx = (int)tt;
            u32 p = s_tab[(dbase + j) * 17 + idx];
            float base = __uint_as_float(p << 16);
            float slope = __uint_as_float(p & 0xffff0000u);
            h[j] = bf16rne(fmaf(slope, tt - (float)idx, base));
        }
        int4 pk = make_int4((int)(h[0] | (h[1] << 16)), (int)(h[2] | (h[3] << 16)),
                            (int)(h[4] | (h[5] << 16)), (int)(h[6] | (h[7] << 16)));
        *reinterpret_cast<int4*>(&sA[awchunk * 8]) = pk;

#pragma unroll
        for (int i = 0; i < 4; i++) {
            int grp = wid * 4 + i;
            int n = grp * 16 + (lane >> 2);
            int c = (lane & 3) ^ ((n >> 1) & 3);
            const u16* gsrc = mixb + (size_t)n * DIMK + kt * 32 + c * 8;
            __builtin_amdgcn_global_load_lds(
                (const __attribute__((address_space(1))) void*)gsrc,
                (__attribute__((address_space(3))) void*)(&sB[grp * 512]),
                16, 0, 0);
        }
        __syncthreads();

        if (kt < 15) {
            xa = xrow[(kt + 1) * 8];
            xb = xrow[(kt + 1) * 8 + 1];
        }

        bf16x8 afrag[4];
#pragma unroll
        for (int fm = 0; fm < 4; fm++) {
            int m_l = wave_m * 64 + fm * 16 + l15;
            int ci = (m_l << 2) | (quad ^ ((m_l >> 1) & 3));
            afrag[fm] = *reinterpret_cast<const bf16x8*>(&sA[ci * 8]);
        }
#pragma unroll
        for (int fn = 0; fn < 8; fn++) {
            int n_l = wave_n * 128 + fn * 16 + l15;
            int ci = (n_l << 2) | (quad ^ ((n_l >> 1) & 3));
            bf16x8 bfrag = *reinterpret_cast<const bf16x8*>(&sB[ci * 8]);
#pragma unroll
            for (int fm = 0; fm < 4; fm++)
                acc[fm][fn] = __builtin_amdgcn_mfma_f32_16x16x32_bf16(
                    afrag[fm], bfrag, acc[fm][fn], 0, 0, 0);
        }
        __syncthreads();
    }

#pragma unroll
    for (int fn = 0; fn < 8; fn++) {
        int o = wave_n * 128 + fn * 16 + l15;
        float bv = bias[o];
#pragma unroll
        for (int fm = 0; fm < 4; fm++) {
            int row = m0 + wave_m * 64 + fm * 16 + quad * 4;
            float* yp = y + (size_t)row * DIMN + o;
#pragma unroll
            for (int j = 0; j < 4; j++)
                yp[(size_t)j * DIMN] = acc[fm][fn][j] + bv;
        }
    }
}

extern "C" void kernel_launch(void* const* d_in, const int* in_sizes, int n_in,
                              void* d_out, int out_size, void* d_ws, size_t ws_size,
                              hipStream_t stream) {
    const float* x = (const float*)d_in[0];
    const float* bases = (const float*)d_in[1];
    const float* slopes = (const float*)d_in[2];
    const float* mix = (const float*)d_in[3];
    const float* bias = (const float*)d_in[4];
    float* y = (float*)d_out;

    u16* mixb = (u16*)d_ws;  // 512 KB
    const size_t need = 512 * 1024 + (size_t)65536 * 512 * 2;  // + 64 MB spline

    hipLaunchKernelGGL(prep_kernel, dim3(256), dim3(256), 0, stream, mix, mixb);

    if (ws_size >= need) {
        u16* spl = (u16*)((char*)d_ws + 512 * 1024);
        hipLaunchKernelGGL(spline_kernel, dim3(1024), dim3(256), 0, stream,
                           x, bases, slopes, spl);
        hipLaunchKernelGGL(gemm_kernel, dim3(512, 4), dim3(256), 0, stream,
                           spl, mixb, bias, y);
    } else {
        hipLaunchKernelGGL(kan_kernel, dim3(512), dim3(512), 0, stream,
                           x, bases, slopes, mixb, bias, y);
    }
}